// Round 15
// baseline (285.293 us; speedup 1.0000x reference)
//
#include <hip/hip_runtime.h>
#include <hip/hip_bf16.h>
#include <math.h>
#include <stdint.h>

typedef __attribute__((ext_vector_type(8))) short bf16x8;
typedef __attribute__((ext_vector_type(4))) float floatx4;

static __device__ __forceinline__ unsigned short f32_to_bf16_rne(float f) {
    union { float f; uint32_t u; } v; v.f = f;
    uint32_t u = v.u;
    return (unsigned short)((u + 0x7fffu + ((u >> 16) & 1u)) >> 16);
}
static __device__ __forceinline__ float bf16_to_f32(unsigned short h) {
    union { uint32_t u; float f; } v; v.u = ((uint32_t)h) << 16;
    return v.f;
}
// 4 float2 -> bf16x8 via HW v_cvt_pk_bf16_f32 (RNE)
static __device__ __forceinline__ bf16x8 cvt8(const float2* p) {
    union { __hip_bfloat162 h[4]; bf16x8 v; } u;
    #pragma unroll
    for (int j = 0; j < 4; ++j)
        u.h[j] = __float22bfloat162_rn({p[j].x, p[j].y});
    return u.v;
}

// LDS-correct barrier that does NOT drain vmcnt (A-burst stays in flight).
#define BAR() do { \
    asm volatile("s_waitcnt lgkmcnt(0)" ::: "memory"); \
    __builtin_amdgcn_s_barrier(); \
    asm volatile("" ::: "memory"); } while (0)

// ---------------------------------------------------------------------------
// Prep: W1a (50x318) -> hi/lo bf16, fragment-ordered (ks-major!):
// byte = ks*8192 + p*4096 + kq*1024 + n*16  (n in [0,64), zero-padded)
// => each K-half (ks 0..4 / 5..9) is one contiguous 40960-B image.
// ---------------------------------------------------------------------------
__global__ void prep_w(const float* __restrict__ W1a, unsigned short* __restrict__ Bpre) {
    int idx = blockIdx.x * 256 + threadIdx.x;
    if (idx >= 40960) return;
    int e  = idx & 7;
    int n  = (idx >> 3) & 63;
    int kq = (idx >> 9) & 3;
    int p  = (idx >> 11) & 1;
    int ks = idx >> 12;
    int k  = ks * 32 + kq * 8 + e;
    float w = (n < 50 && k < 318) ? W1a[n * 318 + k] : 0.0f;
    unsigned short hi = f32_to_bf16_rne(w);
    Bpre[idx] = (p == 0) ? hi : f32_to_bf16_rne(w - bf16_to_f32(hi));
}

// ---------------------------------------------------------------------------
// Fused kernel: 8192 blocks (64-token slab), 256 threads (4 waves), 3/CU.
// Wave wv owns tokens [wv*16,wv*16+16) x all n (m-sliced). A: ONE pinned
// 40x float2 burst direct global->reg (all of the slab's x, rides across all
// barriers). B: two 40KB K-half stages through LDS (lgkm-only barriers).
// Tail fused: h1 patch overlays dead B region, 4x-lane-redundant layer2/3 +
// score, wave softmax partial, block merge, single __syncthreads.
// ---------------------------------------------------------------------------
#define SLAB (64 * 318)
#define H1S 51                 // h1 patch row stride (floats); 19 mod 32 -> conflict-free
#define WPATCH (16 * H1S)      // 816 floats per wave patch
#define PMOFF (4 * WPATCH)     // pm merge area offset (floats) = 13056 B

__global__ __launch_bounds__(256, 3)
void fused_mlp(const float* __restrict__ x,
               const unsigned short* __restrict__ Bpre,
               const float* __restrict__ b1a,
               const float* __restrict__ W1b, const float* __restrict__ b1b,
               const float* __restrict__ W1c, const float* __restrict__ b1c,
               const float* __restrict__ pW1, const float* __restrict__ pb1,
               const float* __restrict__ pW2, const float* __restrict__ pb2,
               float* __restrict__ partials)
{
    __shared__ __align__(16) char bsm[40960];   // B K-half image / later h1+pm

    const int tid  = threadIdx.x;
    const int wv   = tid >> 6;
    const int lane = tid & 63;
    const int fr   = lane & 15;
    const int kq   = lane >> 4;

    const float* arow = x + (size_t)blockIdx.x * SLAB + (wv * 16 + fr) * 318 + kq * 8;

    // ---- issue B K-half-0 stage loads first (oldest), then the FULL A burst
    floatx4 gb[10];
    #pragma unroll
    for (int j = 0; j < 10; ++j)
        gb[j] = *(const floatx4*)((const char*)Bpre + (j * 256 + tid) * 16);

    float2 af[40];
    #pragma unroll
    for (int ks = 0; ks < 10; ++ks)
        #pragma unroll
        for (int j = 0; j < 4; ++j) {
            bool pad = (ks == 9) && (kq == 3) && (j == 3);   // k=318,319
            af[ks * 4 + j] = pad ? make_float2(0.f, 0.f)
                                 : *(const float2*)(arow + ks * 32 + 2 * j);
        }
    __builtin_amdgcn_sched_barrier(0);   // pin all load issue above

    #pragma unroll
    for (int j = 0; j < 10; ++j)
        *(floatx4*)(bsm + (j * 256 + tid) * 16) = gb[j];   // waits B loads only
    BAR();   // K-half-0 B visible; A-burst still outstanding

    floatx4 acc[4];
    #pragma unroll
    for (int nf = 0; nf < 4; ++nf) acc[nf] = (floatx4){0.f, 0.f, 0.f, 0.f};

    // ---- pass 1: ks 0..4
    #pragma unroll
    for (int ks = 0; ks < 5; ++ks) {
        const char* bb = bsm + ks * 8192 + (kq << 10) + (fr << 4);
        bf16x8 a = cvt8(&af[ks * 4]);
        #pragma unroll
        for (int nf = 0; nf < 4; ++nf) {
            bf16x8 bh = *(const bf16x8*)(bb + nf * 256);
            bf16x8 bl = *(const bf16x8*)(bb + 4096 + nf * 256);
            acc[nf] = __builtin_amdgcn_mfma_f32_16x16x32_bf16(a, bh, acc[nf], 0, 0, 0);
            acc[nf] = __builtin_amdgcn_mfma_f32_16x16x32_bf16(a, bl, acc[nf], 0, 0, 0);
        }
    }
    BAR();   // all waves done reading K-half-0

    // ---- stage K-half-1 B (one-time L2 latency, ~600 cy)
    #pragma unroll
    for (int j = 0; j < 10; ++j)
        gb[j] = *(const floatx4*)((const char*)Bpre + 40960 + (j * 256 + tid) * 16);
    #pragma unroll
    for (int j = 0; j < 10; ++j)
        *(floatx4*)(bsm + (j * 256 + tid) * 16) = gb[j];
    BAR();   // K-half-1 B visible

    // ---- pass 2: ks 5..9
    #pragma unroll
    for (int ks = 5; ks < 10; ++ks) {
        const char* bb = bsm + (ks - 5) * 8192 + (kq << 10) + (fr << 4);
        bf16x8 a = cvt8(&af[ks * 4]);
        #pragma unroll
        for (int nf = 0; nf < 4; ++nf) {
            bf16x8 bh = *(const bf16x8*)(bb + nf * 256);
            bf16x8 bl = *(const bf16x8*)(bb + 4096 + nf * 256);
            acc[nf] = __builtin_amdgcn_mfma_f32_16x16x32_bf16(a, bh, acc[nf], 0, 0, 0);
            acc[nf] = __builtin_amdgcn_mfma_f32_16x16x32_bf16(a, bl, acc[nf], 0, 0, 0);
        }
    }
    BAR();   // all waves done reading B -> bsm reusable for h1 patches

    // ---- bias + ReLU -> wave-private h1 patch [16 tokens][51]
    // D layout: lane (fr,kq): acc[nf][r] = h1[token kq*4+r][n = nf*16+fr]
    float* h1p = (float*)bsm + wv * WPATCH;
    #pragma unroll
    for (int nf = 0; nf < 4; ++nf) {
        int n = nf * 16 + fr;
        if (n < 50) {
            float bia = b1a[n];
            #pragma unroll
            for (int r = 0; r < 4; ++r)
                h1p[(kq * 4 + r) * H1S + n] = fmaxf(acc[nf][r] + bia, 0.0f);
        }
    }
    asm volatile("s_waitcnt lgkmcnt(0)" ::: "memory");   // intra-wave ordering

    // ---- tail: token = fr (4 kq lane-groups redundant); layers 2/3 + score
    const float* h1r = h1p + fr * H1S;

    float h2[20];
    #pragma unroll
    for (int o = 0; o < 20; ++o) h2[o] = b1b[o];
    #pragma unroll
    for (int i = 0; i < 50; ++i) {
        float hv = h1r[i];
        #pragma unroll
        for (int o = 0; o < 20; ++o) h2[o] = fmaf(hv, W1b[o * 50 + i], h2[o]);
    }
    #pragma unroll
    for (int o = 0; o < 20; ++o) h2[o] = fmaxf(h2[o], 0.0f);

    float h3[20];
    #pragma unroll
    for (int o = 0; o < 20; ++o) {
        float a = b1c[o];
        const float* w = W1c + o * 20;
        #pragma unroll
        for (int i = 0; i < 20; ++i) a = fmaf(h2[i], w[i], a);
        h3[o] = fmaxf(a, 0.0f);
    }

    float s = pb2[0];
    #pragma unroll
    for (int j = 0; j < 10; ++j) {
        float a = pb1[j];
        const float* w = pW1 + j * 20;
        #pragma unroll
        for (int i = 0; i < 20; ++i) a = fmaf(h3[i], w[i], a);
        s = fmaf(fmaxf(a, 0.0f), pW2[j], s);
    }

    // softmax partial over the wave's 16 tokens (reduce over fr bits)
    float m = s;
    #pragma unroll
    for (int d = 8; d > 0; d >>= 1) m = fmaxf(m, __shfl_xor(m, d));
    float e = expf(s - m);
    float S = e;
    #pragma unroll
    for (int d = 8; d > 0; d >>= 1) S += __shfl_xor(S, d);

    float V[20];
    #pragma unroll
    for (int o = 0; o < 20; ++o) {
        float v = e * h3[o];
        #pragma unroll
        for (int d = 8; d > 0; d >>= 1) v += __shfl_xor(v, d);
        V[o] = v;
    }

    // wave partial {m, S, V[20]} -> pm[wv] (region beyond the 4 h1 patches)
    float* pm = (float*)bsm + PMOFF;
    {
        float myv = m;
        if (lane == 1) myv = S;
        #pragma unroll
        for (int o = 0; o < 20; ++o) if (lane == o + 2) myv = V[o];
        if (lane < 22) pm[wv * 24 + lane] = myv;
    }
    __syncthreads();   // final block barrier (nothing left in flight)

    // wave 0 merges the 4 wave-partials -> 64-token partial
    if (wv == 0 && lane < 22) {
        float m0 = pm[0], m1 = pm[24], m2 = pm[48], m3 = pm[72];
        float mm = fmaxf(fmaxf(m0, m1), fmaxf(m2, m3));
        float w0 = expf(m0 - mm), w1 = expf(m1 - mm);
        float w2 = expf(m2 - mm), w3 = expf(m3 - mm);
        float outv;
        if (lane == 0) {
            outv = mm;
        } else {
            float v0 = pm[lane], v1 = pm[24 + lane];
            float v2 = pm[48 + lane], v3 = pm[72 + lane];
            outv = fmaf(v0, w0, fmaf(v1, w1, fmaf(v2, w2, v3 * w3)));
        }
        partials[(size_t)blockIdx.x * 24 + lane] = outv;
    }
}

// ---------------------------------------------------------------------------
// Kernel B: combine half-group partials, pool over G=128, normalize, head.
// ---------------------------------------------------------------------------
__global__ __launch_bounds__(128, 4)
void pool_g_head(const float* __restrict__ partials,
                 const float* __restrict__ qW1, const float* __restrict__ qb1,
                 const float* __restrict__ qW2, const float* __restrict__ qb2,
                 const float* __restrict__ W3a, const float* __restrict__ b3a,
                 const float* __restrict__ W3b, const float* __restrict__ b3b,
                 float* __restrict__ out)
{
    __shared__ float red_m[2];
    __shared__ float red_s[2];
    __shared__ float part[2][20];

    const int tid = threadIdx.x;      // g
    const int b = blockIdx.x;
    const float* P = partials + ((size_t)(b * 128 + tid)) * 48;

    float m0 = P[0], S0 = P[1], m1 = P[24], S1 = P[25];
    float m = fmaxf(m0, m1);
    float w0 = expf(m0 - m), w1 = expf(m1 - m);
    float den = fmaf(S0, w0, S1 * w1);

    float v[20];
    #pragma unroll
    for (int o = 0; o < 20; ++o)
        v[o] = fmaf(P[2 + o], w0, P[26 + o] * w1) / den;

    float s = qb2[0];
    #pragma unroll
    for (int j = 0; j < 10; ++j) {
        float a = qb1[j];
        const float* w = qW1 + j * 20;
        #pragma unroll
        for (int i = 0; i < 20; ++i) a = fmaf(v[i], w[i], a);
        s = fmaf(fmaxf(a, 0.0f), qW2[j], s);
    }

    const int wig = tid >> 6, lane = tid & 63;
    float mm = s;
    #pragma unroll
    for (int d = 32; d > 0; d >>= 1) mm = fmaxf(mm, __shfl_xor(mm, d));
    if (lane == 0) red_m[wig] = mm;
    __syncthreads();
    mm = fmaxf(red_m[0], red_m[1]);

    float e = expf(s - mm);
    float su = e;
    #pragma unroll
    for (int d = 32; d > 0; d >>= 1) su += __shfl_xor(su, d);
    if (lane == 0) red_s[wig] = su;

    #pragma unroll
    for (int o = 0; o < 20; ++o) {
        float val = e * v[o];
        #pragma unroll
        for (int d = 32; d > 0; d >>= 1) val += __shfl_xor(val, d);
        if (lane == 0) part[wig][o] = val;
    }
    __syncthreads();

    if (tid == 0) {
        float dg = red_s[0] + red_s[1];
        float rb[20];
        float n2 = 0.0f;
        #pragma unroll
        for (int o = 0; o < 20; ++o) {
            rb[o] = (part[0][o] + part[1][o]) / dg;
            n2 = fmaf(rb[o], rb[o], n2);
        }
        float nrm = fmaxf(sqrtf(n2), 1e-12f);
        #pragma unroll
        for (int o = 0; o < 20; ++o) rb[o] /= nrm;

        float accv = b3b[0];
        #pragma unroll
        for (int j = 0; j < 10; ++j) {
            float a = b3a[j];
            const float* w = W3a + j * 20;
            #pragma unroll
            for (int i = 0; i < 20; ++i) a = fmaf(rb[i], w[i], a);
            accv = fmaf(fmaxf(a, 0.0f), W3b[j], accv);
        }
        out[b] = accv;
    }
}

extern "C" void kernel_launch(void* const* d_in, const int* in_sizes, int n_in,
                              void* d_out, int out_size, void* d_ws, size_t ws_size,
                              hipStream_t stream) {
    const float* x   = (const float*)d_in[0];
    const float* W1a = (const float*)d_in[1];
    const float* b1a = (const float*)d_in[2];
    const float* W1b = (const float*)d_in[3];
    const float* b1b = (const float*)d_in[4];
    const float* W1c = (const float*)d_in[5];
    const float* b1c = (const float*)d_in[6];
    const float* pW1 = (const float*)d_in[7];
    const float* pb1 = (const float*)d_in[8];
    const float* pW2 = (const float*)d_in[9];
    const float* pb2 = (const float*)d_in[10];
    const float* qW1 = (const float*)d_in[11];
    const float* qb1 = (const float*)d_in[12];
    const float* qW2 = (const float*)d_in[13];
    const float* qb2 = (const float*)d_in[14];
    const float* W3a = (const float*)d_in[15];
    const float* b3a = (const float*)d_in[16];
    const float* W3b = (const float*)d_in[17];
    const float* b3b = (const float*)d_in[18];

    float* partials      = (float*)d_ws;                              // 786,432 B
    unsigned short* Bpre = (unsigned short*)((char*)d_ws + 786432);   // 81,920 B

    prep_w<<<160, 256, 0, stream>>>(W1a, Bpre);
    fused_mlp<<<8192, 256, 0, stream>>>(
        x, Bpre, b1a, W1b, b1b, W1c, b1c, pW1, pb1, pW2, pb2, partials);
    pool_g_head<<<32, 128, 0, stream>>>(
        partials, qW1, qb1, qW2, qb2, W3a, b3a, W3b, b3b, (float*)d_out);
}

// Round 16
// 241.967 us; speedup vs baseline: 1.1791x; 1.1791x over previous
//
#include <hip/hip_runtime.h>
#include <hip/hip_bf16.h>
#include <math.h>
#include <stdint.h>

typedef __attribute__((ext_vector_type(8))) short bf16x8;
typedef __attribute__((ext_vector_type(4))) float floatx4;

static __device__ __forceinline__ unsigned short f32_to_bf16_rne(float f) {
    union { float f; uint32_t u; } v; v.f = f;
    uint32_t u = v.u;
    return (unsigned short)((u + 0x7fffu + ((u >> 16) & 1u)) >> 16);
}
static __device__ __forceinline__ float bf16_to_f32(unsigned short h) {
    union { uint32_t u; float f; } v; v.u = ((uint32_t)h) << 16;
    return v.f;
}
// 8 fp32 (two float4) -> bf16x8 via HW v_cvt_pk_bf16_f32 (RNE)
static __device__ __forceinline__ bf16x8 cvt8(float4 a, float4 b) {
    union { __hip_bfloat162 h[4]; bf16x8 v; } u;
    u.h[0] = __float22bfloat162_rn({a.x, a.y});
    u.h[1] = __float22bfloat162_rn({a.z, a.w});
    u.h[2] = __float22bfloat162_rn({b.x, b.y});
    u.h[3] = __float22bfloat162_rn({b.z, b.w});
    return u.v;
}

// LDS-correct barrier that does NOT drain vmcnt (A-burst stays in flight).
#define BAR() do { \
    asm volatile("s_waitcnt lgkmcnt(0)" ::: "memory"); \
    __builtin_amdgcn_s_barrier(); \
    asm volatile("" ::: "memory"); } while (0)

// ---------------------------------------------------------------------------
// Prep: W1a (50x318) -> hi/lo bf16, fragment-ordered (ks-major):
// byte = ks*8192 + p*4096 + kq*1024 + n*16  (n in [0,64), zero-padded)
// => each K-half (ks 0..4 / 5..9) is one contiguous 40960-B image.
// ---------------------------------------------------------------------------
__global__ void prep_w(const float* __restrict__ W1a, unsigned short* __restrict__ Bpre) {
    int idx = blockIdx.x * 256 + threadIdx.x;
    if (idx >= 40960) return;
    int e  = idx & 7;
    int n  = (idx >> 3) & 63;
    int kq = (idx >> 9) & 3;
    int p  = (idx >> 11) & 1;
    int ks = idx >> 12;
    int k  = ks * 32 + kq * 8 + e;
    float w = (n < 50 && k < 318) ? W1a[n * 318 + k] : 0.0f;
    unsigned short hi = f32_to_bf16_rne(w);
    Bpre[idx] = (p == 0) ? hi : f32_to_bf16_rne(w - bf16_to_f32(hi));
}

// ---------------------------------------------------------------------------
// Kernel A (pure GEMM): 8192 blocks (64-token slab), 256 threads (4 waves),
// 3 blocks/CU (LDS 40960). Wave wv owns tokens [wv*16,wv*16+16) x all n.
// A: ONE pinned 20x float4 burst direct global->reg (rides across all
// barriers). B: two 40KB K-half stages through LDS; half-1 loads issued
// before the first barrier (L2 latency hidden under pass 1). 3 lgkm-only
// barriers. bias+ReLU -> h1 to global ws. No tail (split kernel).
// ---------------------------------------------------------------------------
#define SLAB (64 * 318)
#define H1S 52     // h1 global row stride (floats): 208 B, 16B-aligned

__global__ __launch_bounds__(256, 3)
void gemm_h1(const float* __restrict__ x,
             const unsigned short* __restrict__ Bpre,
             const float* __restrict__ b1a,
             float* __restrict__ h1g)
{
    __shared__ __align__(16) char bsm[40960];   // one B K-half image

    const int tid  = threadIdx.x;
    const int wv   = tid >> 6;
    const int lane = tid & 63;
    const int fr   = lane & 15;
    const int kq   = lane >> 4;

    const float* arow = x + (size_t)blockIdx.x * SLAB + (wv * 16 + fr) * 318 + kq * 8;

    // ---- issue B half-0 loads first (oldest), then the FULL A burst
    floatx4 gb[10];
    #pragma unroll
    for (int j = 0; j < 10; ++j)
        gb[j] = *(const floatx4*)((const char*)Bpre + (j * 256 + tid) * 16);

    float4 af[20];
    #pragma unroll
    for (int ks = 0; ks < 10; ++ks)
        #pragma unroll
        for (int j = 0; j < 2; ++j) {
            if (ks == 9 && kq == 3 && j == 1) {     // k=316..319: pad 318,319
                float2 t = *(const float2*)(arow + 9 * 32 + 4);
                af[19] = make_float4(t.x, t.y, 0.f, 0.f);
            } else {
                af[ks * 2 + j] = *(const float4*)(arow + ks * 32 + 4 * j);
            }
        }
    __builtin_amdgcn_sched_barrier(0);   // pin all load issue above

    // write half-0 to LDS (waits only the B loads; A stays in flight),
    // then issue half-1 B loads (latency hides under pass 1)
    #pragma unroll
    for (int j = 0; j < 10; ++j)
        *(floatx4*)(bsm + (j * 256 + tid) * 16) = gb[j];
    #pragma unroll
    for (int j = 0; j < 10; ++j)
        gb[j] = *(const floatx4*)((const char*)Bpre + 40960 + (j * 256 + tid) * 16);
    __builtin_amdgcn_sched_barrier(0);
    BAR();   // half-0 visible; A-burst + half-1 loads still outstanding

    floatx4 acc[4];
    #pragma unroll
    for (int nf = 0; nf < 4; ++nf) acc[nf] = (floatx4){0.f, 0.f, 0.f, 0.f};

    // ---- pass 1: ks 0..4
    #pragma unroll
    for (int ks = 0; ks < 5; ++ks) {
        const char* bb = bsm + ks * 8192 + (kq << 10) + (fr << 4);
        bf16x8 a = cvt8(af[ks * 2], af[ks * 2 + 1]);
        #pragma unroll
        for (int nf = 0; nf < 4; ++nf) {
            bf16x8 bh = *(const bf16x8*)(bb + nf * 256);
            bf16x8 bl = *(const bf16x8*)(bb + 4096 + nf * 256);
            acc[nf] = __builtin_amdgcn_mfma_f32_16x16x32_bf16(a, bh, acc[nf], 0, 0, 0);
            acc[nf] = __builtin_amdgcn_mfma_f32_16x16x32_bf16(a, bl, acc[nf], 0, 0, 0);
        }
    }
    BAR();   // all waves done reading half-0

    #pragma unroll
    for (int j = 0; j < 10; ++j)
        *(floatx4*)(bsm + (j * 256 + tid) * 16) = gb[j];   // half-1 (already landed)
    BAR();   // half-1 visible

    // ---- pass 2: ks 5..9
    #pragma unroll
    for (int ks = 5; ks < 10; ++ks) {
        const char* bb = bsm + (ks - 5) * 8192 + (kq << 10) + (fr << 4);
        bf16x8 a = cvt8(af[ks * 2], af[ks * 2 + 1]);
        #pragma unroll
        for (int nf = 0; nf < 4; ++nf) {
            bf16x8 bh = *(const bf16x8*)(bb + nf * 256);
            bf16x8 bl = *(const bf16x8*)(bb + 4096 + nf * 256);
            acc[nf] = __builtin_amdgcn_mfma_f32_16x16x32_bf16(a, bh, acc[nf], 0, 0, 0);
            acc[nf] = __builtin_amdgcn_mfma_f32_16x16x32_bf16(a, bl, acc[nf], 0, 0, 0);
        }
    }

    // ---- bias + ReLU -> h1 global [token][52]
    // D layout: lane (fr,kq): acc[nf][r] = h1[token kq*4+r][n = nf*16+fr]
    {
        float* hrow = h1g + ((size_t)blockIdx.x * 64 + wv * 16 + kq * 4) * H1S;
        #pragma unroll
        for (int nf = 0; nf < 4; ++nf) {
            int n = nf * 16 + fr;
            if (n < 50) {
                float bia = b1a[n];
                #pragma unroll
                for (int r = 0; r < 4; ++r)
                    hrow[r * H1S + n] = fmaxf(acc[nf][r] + bia, 0.0f);
            }
        }
    }
}

// ---------------------------------------------------------------------------
// Kernel T: tail. 2048 blocks x 256 threads; thread = token; wave = one
// 64-token slab. layer2/3 + score + wave softmax partial {m,S,V[20]} -> ws.
// ---------------------------------------------------------------------------
__global__ __launch_bounds__(256, 4)
void tail_pool(const float* __restrict__ h1g,
               const float* __restrict__ W1b, const float* __restrict__ b1b,
               const float* __restrict__ W1c, const float* __restrict__ b1c,
               const float* __restrict__ pW1, const float* __restrict__ pb1,
               const float* __restrict__ pW2, const float* __restrict__ pb2,
               float* __restrict__ partials)
{
    const int t    = blockIdx.x * 256 + threadIdx.x;   // global token id
    const int lane = threadIdx.x & 63;

    float hv[52];
    {
        const float4* hr = (const float4*)(h1g + (size_t)t * H1S);
        #pragma unroll
        for (int j = 0; j < 13; ++j) {
            float4 u = hr[j];
            hv[4 * j] = u.x; hv[4 * j + 1] = u.y;
            hv[4 * j + 2] = u.z; hv[4 * j + 3] = u.w;
        }
    }

    float h2[20];
    #pragma unroll
    for (int o = 0; o < 20; ++o) h2[o] = b1b[o];
    #pragma unroll
    for (int i = 0; i < 50; ++i) {
        float hvv = hv[i];
        #pragma unroll
        for (int o = 0; o < 20; ++o) h2[o] = fmaf(hvv, W1b[o * 50 + i], h2[o]);
    }
    #pragma unroll
    for (int o = 0; o < 20; ++o) h2[o] = fmaxf(h2[o], 0.0f);

    float h3[20];
    #pragma unroll
    for (int o = 0; o < 20; ++o) {
        float a = b1c[o];
        const float* w = W1c + o * 20;
        #pragma unroll
        for (int i = 0; i < 20; ++i) a = fmaf(h2[i], w[i], a);
        h3[o] = fmaxf(a, 0.0f);
    }

    float s = pb2[0];
    #pragma unroll
    for (int j = 0; j < 10; ++j) {
        float a = pb1[j];
        const float* w = pW1 + j * 20;
        #pragma unroll
        for (int i = 0; i < 20; ++i) a = fmaf(h3[i], w[i], a);
        s = fmaf(fmaxf(a, 0.0f), pW2[j], s);
    }

    float m = s;
    #pragma unroll
    for (int d = 32; d > 0; d >>= 1) m = fmaxf(m, __shfl_xor(m, d));
    float e = expf(s - m);
    float S = e;
    #pragma unroll
    for (int d = 32; d > 0; d >>= 1) S += __shfl_xor(S, d);

    float V[20];
    #pragma unroll
    for (int o = 0; o < 20; ++o) {
        float v = e * h3[o];
        #pragma unroll
        for (int d = 32; d > 0; d >>= 1) v += __shfl_xor(v, d);
        V[o] = v;
    }

    float myv = m;
    if (lane == 1) myv = S;
    #pragma unroll
    for (int o = 0; o < 20; ++o) if (lane == o + 2) myv = V[o];
    if (lane < 22) partials[(size_t)(t >> 6) * 24 + lane] = myv;
}

// ---------------------------------------------------------------------------
// Kernel B: combine half-group partials, pool over G=128, normalize, head.
// ---------------------------------------------------------------------------
__global__ __launch_bounds__(128, 4)
void pool_g_head(const float* __restrict__ partials,
                 const float* __restrict__ qW1, const float* __restrict__ qb1,
                 const float* __restrict__ qW2, const float* __restrict__ qb2,
                 const float* __restrict__ W3a, const float* __restrict__ b3a,
                 const float* __restrict__ W3b, const float* __restrict__ b3b,
                 float* __restrict__ out)
{
    __shared__ float red_m[2];
    __shared__ float red_s[2];
    __shared__ float part[2][20];

    const int tid = threadIdx.x;      // g
    const int b = blockIdx.x;
    const float* P = partials + ((size_t)(b * 128 + tid)) * 48;

    float m0 = P[0], S0 = P[1], m1 = P[24], S1 = P[25];
    float m = fmaxf(m0, m1);
    float w0 = expf(m0 - m), w1 = expf(m1 - m);
    float den = fmaf(S0, w0, S1 * w1);

    float v[20];
    #pragma unroll
    for (int o = 0; o < 20; ++o)
        v[o] = fmaf(P[2 + o], w0, P[26 + o] * w1) / den;

    float s = qb2[0];
    #pragma unroll
    for (int j = 0; j < 10; ++j) {
        float a = qb1[j];
        const float* w = qW1 + j * 20;
        #pragma unroll
        for (int i = 0; i < 20; ++i) a = fmaf(v[i], w[i], a);
        s = fmaf(fmaxf(a, 0.0f), qW2[j], s);
    }

    const int wig = tid >> 6, lane = tid & 63;
    float mm = s;
    #pragma unroll
    for (int d = 32; d > 0; d >>= 1) mm = fmaxf(mm, __shfl_xor(mm, d));
    if (lane == 0) red_m[wig] = mm;
    __syncthreads();
    mm = fmaxf(red_m[0], red_m[1]);

    float e = expf(s - mm);
    float su = e;
    #pragma unroll
    for (int d = 32; d > 0; d >>= 1) su += __shfl_xor(su, d);
    if (lane == 0) red_s[wig] = su;

    #pragma unroll
    for (int o = 0; o < 20; ++o) {
        float val = e * v[o];
        #pragma unroll
        for (int d = 32; d > 0; d >>= 1) val += __shfl_xor(val, d);
        if (lane == 0) part[wig][o] = val;
    }
    __syncthreads();

    if (tid == 0) {
        float dg = red_s[0] + red_s[1];
        float rb[20];
        float n2 = 0.0f;
        #pragma unroll
        for (int o = 0; o < 20; ++o) {
            rb[o] = (part[0][o] + part[1][o]) / dg;
            n2 = fmaf(rb[o], rb[o], n2);
        }
        float nrm = fmaxf(sqrtf(n2), 1e-12f);
        #pragma unroll
        for (int o = 0; o < 20; ++o) rb[o] /= nrm;

        float accv = b3b[0];
        #pragma unroll
        for (int j = 0; j < 10; ++j) {
            float a = b3a[j];
            const float* w = W3a + j * 20;
            #pragma unroll
            for (int i = 0; i < 20; ++i) a = fmaf(rb[i], w[i], a);
            accv = fmaf(fmaxf(a, 0.0f), W3b[j], accv);
        }
        out[b] = accv;
    }
}

extern "C" void kernel_launch(void* const* d_in, const int* in_sizes, int n_in,
                              void* d_out, int out_size, void* d_ws, size_t ws_size,
                              hipStream_t stream) {
    const float* x   = (const float*)d_in[0];
    const float* W1a = (const float*)d_in[1];
    const float* b1a = (const float*)d_in[2];
    const float* W1b = (const float*)d_in[3];
    const float* b1b = (const float*)d_in[4];
    const float* W1c = (const float*)d_in[5];
    const float* b1c = (const float*)d_in[6];
    const float* pW1 = (const float*)d_in[7];
    const float* pb1 = (const float*)d_in[8];
    const float* pW2 = (const float*)d_in[9];
    const float* pb2 = (const float*)d_in[10];
    const float* qW1 = (const float*)d_in[11];
    const float* qb1 = (const float*)d_in[12];
    const float* qW2 = (const float*)d_in[13];
    const float* qb2 = (const float*)d_in[14];
    const float* W3a = (const float*)d_in[15];
    const float* b3a = (const float*)d_in[16];
    const float* W3b = (const float*)d_in[17];
    const float* b3b = (const float*)d_in[18];

    float* partials      = (float*)d_ws;                              // 786,432 B
    unsigned short* Bpre = (unsigned short*)((char*)d_ws + 786432);   // 81,920 B
    float* h1g           = (float*)((char*)d_ws + 868352);            // 109 MB

    prep_w<<<160, 256, 0, stream>>>(W1a, Bpre);
    gemm_h1<<<8192, 256, 0, stream>>>(x, Bpre, b1a, h1g);
    tail_pool<<<2048, 256, 0, stream>>>(
        h1g, W1b, b1b, W1c, b1c, pW1, pb1, pW2, pb2, partials);
    pool_g_head<<<32, 128, 0, stream>>>(
        partials, qW1, qb1, qW2, qb2, W3a, b3a, W3b, b3b, (float*)d_out);
}